// Round 1
// 293.488 us; speedup vs baseline: 1.1071x; 1.1071x over previous
//
#include <hip/hip_runtime.h>

#define EPSBN 1e-5f

typedef _Float16 f16;
typedef _Float16 f16x8 __attribute__((ext_vector_type(8)));
typedef _Float16 f16x4 __attribute__((ext_vector_type(4)));
typedef _Float16 f16x2 __attribute__((ext_vector_type(2)));
typedef float    f32x4 __attribute__((ext_vector_type(4)));

__device__ inline unsigned int pack2(float a, float b) {
    union { f16x2 h; unsigned int u; } cv;
    cv.h[0] = (f16)a; cv.h[1] = (f16)b;
    return cv.u;
}
__device__ inline f16x4 hmax4(f16x4 a, f16x4 b) {
    f16x4 r;
    #pragma unroll
    for (int i = 0; i < 4; ++i) r[i] = a[i] > b[i] ? a[i] : b[i];
    return r;
}
__device__ inline f16x8 relu8(f16x8 v) {
    f16x8 r;
    #pragma unroll
    for (int i = 0; i < 8; ++i) r[i] = v[i] > (f16)0.f ? v[i] : (f16)0.f;
    return r;
}

// ---------------------------------------------------------------------------
// wprep: weights -> f16.  fc1w [0,32768) ; w1 [32768,40960) ;
// w2 as [tau][o][i] [40960,53248) ; w3 [53248,61440)
// ---------------------------------------------------------------------------
__global__ void wprep_kernel(const float* __restrict__ fc1w,
                             const float* __restrict__ w1,
                             const float* __restrict__ w2,
                             const float* __restrict__ w3,
                             f16* __restrict__ dst) {
    const int i = blockIdx.x * 256 + threadIdx.x;   // 61440 total
    float v;
    if (i < 32768)      v = fc1w[i];
    else if (i < 40960) v = w1[i - 32768];
    else if (i < 53248) {
        const int j = i - 40960, tau = j >> 12, rest = j & 4095;
        v = w2[rest * 3 + tau];
    } else              v = w3[i - 53248];
    dst[i] = (f16)v;
}

// ---------------------------------------------------------------------------
// fc1 v2: 256-point tiles, contiguous 1 KB channel-row streaming.
//
// Old version read 256 B column slices -> every wave-instruction touched 32
// cache lines 64 KB apart -> fabric capped at ~1.7 TB/s (97.6 us, MfmaUtil
// 3.3%).  Now: grid = 8 img x 64 tiles (img = bid&7 keeps XCD pinning),
// 512 threads.  K is staged 32 channels at a time, double-buffered:
// global_load_lds_dwordx4 streams one FULL 1 KB channel row per instruction
// (64 lanes x 16 B contiguous, linear LDS dest as required).  The pt<->ch
// transpose happens at LDS->reg: B-frags built from 8 scalar f32 reads + cvt
// (channel rows offset by (ch>>3)*64 B -> exactly 2-way bank = free).
// W is the A operand so D = [o][pt]; epilogue goes through LDS for
// full-row (256 B) coalesced xmap writes.
// LDS 69.6 KB -> 2 blocks/CU; __launch_bounds__(512,4) caps VGPR at 128.
// ---------------------------------------------------------------------------
__global__ __launch_bounds__(512, 4)
void fc1_mfma(const float* __restrict__ feat,   // [8][256][16384] f32
              const f16*   __restrict__ w16,    // [128][256] f16
              const float* __restrict__ bias,   // [128]
              f16*         __restrict__ xmap) { // [8][16384][128] f16
    __shared__ union {
        float fbuf[2][8368];          // 2 x 33472 B: 32 ch x 260 dw (+16 dw per 8-ch group)
        f16   epi[256][136];          // 69632 B epilogue staging
    } u;

    const int tid  = threadIdx.x;
    const int wv   = tid >> 6, lane = tid & 63;
    const int n16  = lane & 15, quad = lane >> 4;
    const int img  = blockIdx.x & 7;              // XCD pin (same as loi)
    const int p0   = (blockIdx.x >> 3) << 8;      // 256-pt tile

    const float* fimg = feat + (((size_t)img) << 22);

    f32x4 acc[8][2];
    #pragma unroll
    for (int ot = 0; ot < 8; ++ot) {
        acc[ot][0] = (f32x4){0.f, 0.f, 0.f, 0.f};
        acc[ot][1] = (f32x4){0.f, 0.f, 0.f, 0.f};
    }

    // issue one K-stage (32 channels) of contiguous 1 KB rows into buf b
    auto issue = [&](int s, int b) {
        #pragma unroll
        for (int i = 0; i < 4; ++i) {
            const int cl = wv * 4 + i;            // local channel 0..31
            const int ch = s * 32 + cl;
            const float* src = fimg + (((size_t)ch) << 14) + p0 + lane * 4;
            float* dst = &u.fbuf[b][cl * 260 + (cl >> 3) * 16];  // wave-uniform base
            __builtin_amdgcn_global_load_lds(
                (const __attribute__((address_space(1))) void*)src,
                (__attribute__((address_space(3))) void*)dst, 16, 0, 0);
        }
    };

    issue(0, 0);
    __syncthreads();                               // drains vmcnt -> buf0 ready

    for (int s = 0; s < 8; ++s) {
        const int cur = s & 1;
        if (s < 7) issue(s + 1, cur ^ 1);          // prefetch next stage

        // build B-frags (x): lane(n16,quad) holds x[k=quad*8+j][pt=base+n16]
        f16x8 xf[2];
        #pragma unroll
        for (int pt = 0; pt < 2; ++pt) {
            const int pbase = wv * 32 + pt * 16 + n16;
            const float* fb = &u.fbuf[cur][quad * 16 + pbase];
            f16x8 xv;
            #pragma unroll
            for (int j = 0; j < 8; ++j)
                xv[j] = (f16)fb[(quad * 8 + j) * 260];
            xf[pt] = xv;
        }

        // A-frags (W, L2-hot): lane(n16,quad) holds W[o=ot*16+n16][k=quad*8+j]
        const f16* wrow = w16 + (size_t)n16 * 256 + s * 32 + quad * 8;
        #pragma unroll
        for (int ot = 0; ot < 8; ++ot) {
            const f16x8 wf = *(const f16x8*)(wrow + ot * 4096);
            acc[ot][0] = __builtin_amdgcn_mfma_f32_16x16x32_f16(wf, xf[0], acc[ot][0], 0, 0, 0);
            acc[ot][1] = __builtin_amdgcn_mfma_f32_16x16x32_f16(wf, xf[1], acc[ot][1], 0, 0, 0);
        }
        __syncthreads();                           // next buf ready; fbuf[cur] free
    }

    // epilogue: D[o][pt] row = quad*4+r (o), col = n16 (pt) -> LDS -> coalesced rows
    #pragma unroll
    for (int ot = 0; ot < 8; ++ot) {
        const float4 bq = *(const float4*)&bias[ot * 16 + quad * 4];
        const float bqa[4] = {bq.x, bq.y, bq.z, bq.w};
        #pragma unroll
        for (int pt = 0; pt < 2; ++pt) {
            f16x4 h;
            #pragma unroll
            for (int r = 0; r < 4; ++r) h[r] = (f16)(acc[ot][pt][r] + bqa[r]);
            *(f16x4*)&u.epi[wv * 32 + pt * 16 + n16][ot * 16 + quad * 4] = h;
        }
    }
    __syncthreads();

    #pragma unroll
    for (int it = 0; it < 8; ++it) {
        const int idx = it * 512 + tid;
        const int row = idx >> 4, seg = idx & 15;
        const float4 v = *(const float4*)&u.epi[row][seg * 8];
        *(float4*)&xmap[(((size_t)(img * 16384 + p0 + row)) << 7) + seg * 8] = v;
    }
}

// ---------------------------------------------------------------------------
// loi: 8 lines/block, image = blockIdx & 7 (XCD-pinned: gathers stay in the
// XCD L2 that fc1 just filled).  Sampling in packed f16 (4 ch/lane, 8B loads)
// -> xp[64n][128c] f16 -> conv1/conv2/conv3 MFMA -> residual+relu+fc2.
// ---------------------------------------------------------------------------
__global__ __launch_bounds__(256)
void loi_kernel(const f16*   __restrict__ x,       // [8][16384][128] f16
                const float* __restrict__ lines,
                const f16*   __restrict__ wsp,
                const float* __restrict__ bn1g, const float* __restrict__ bn1b,
                const float* __restrict__ bn1m, const float* __restrict__ bn1v,
                const float* __restrict__ b1,
                const float* __restrict__ bn2g, const float* __restrict__ bn2b,
                const float* __restrict__ bn2m, const float* __restrict__ bn2v,
                const float* __restrict__ b2,
                const float* __restrict__ bn3g, const float* __restrict__ bn3b,
                const float* __restrict__ bn3m, const float* __restrict__ bn3v,
                const float* __restrict__ b3,
                const float* __restrict__ fc2w, const float* __restrict__ fc2b,
                float* __restrict__ out) {
    __shared__ f16 xp[64][136];                       // 17408 B
    __shared__ alignas(16) union {
        struct { int toff[256][4]; f16 twgt[256][4]; } tp;     // 6144 B
        struct { f16 h1[80][72]; f16 h2[64][72]; } cv;         // 20736 B
    } u;
    __shared__ f16 s1h[128], t1h[128];                // 512 B
    __shared__ float s2f[64], t2f[64], s3f[64], t3f[64], b1f[64], b2f[64];
    __shared__ float b3f[128];
    __shared__ float wsum[4][8];

    const f16* w1f16 = wsp + 32768;
    const f16* w2f16 = wsp + 40960;
    const f16* w3f16 = wsp + 53248;

    const int tid  = threadIdx.x;
    const int wv   = tid >> 6, lane = tid & 63;
    const int n16  = lane & 15, quad = lane >> 4;
    const int img  = blockIdx.x & 7;                  // XCD swizzle
    const int mblk = blockIdx.x >> 3;                 // 0..255 within image

    // ---- LUTs ----
    if (tid < 128) {
        const float s = bn1g[tid] * rsqrtf(bn1v[tid] + EPSBN);
        s1h[tid] = (f16)s; t1h[tid] = (f16)(bn1b[tid] - bn1m[tid] * s);
    }
    if (tid < 64) {
        const float s = bn2g[tid] * rsqrtf(bn2v[tid] + EPSBN);
        s2f[tid] = s; t2f[tid] = bn2b[tid] - bn2m[tid] * s;
        b1f[tid] = b1[tid];
    } else if (tid < 128) {
        const int c = tid - 64;
        const float s = bn3g[c] * rsqrtf(bn3v[c] + EPSBN);
        s3f[c] = s; t3f[c] = bn3b[c] - bn3m[c] * s;
        b2f[c] = b2[c];
    } else {
        b3f[tid - 128] = b3[tid - 128];
    }

    // ---- interp tuples: one per (line, pt) ----
    {
        const int li = tid >> 5, pt = tid & 31;
        const int gl = img * 2048 + mblk * 8 + li;
        const float4 ln = *(const float4*)&lines[gl * 4];
        const float lam = (float)pt * (1.0f / 31.0f);
        const float px = ln.x * lam + ln.z * (1.f - lam) - 0.5f;
        const float py = ln.y * lam + ln.w * (1.f - lam) - 0.5f;
        const float px0 = fminf(fmaxf(floorf(px), 0.f), 127.f);
        const float py0 = fminf(fmaxf(floorf(py), 0.f), 127.f);
        const float px1 = fminf(px0 + 1.f, 127.f);
        const float py1 = fminf(py0 + 1.f, 127.f);
        const int ix0 = (int)px0, iy0 = (int)py0;
        const int ix1 = (int)px1, iy1 = (int)py1;
        u.tp.toff[tid][0] = (((ix0 << 7) + iy0) << 7);
        u.tp.toff[tid][1] = (((ix1 << 7) + iy0) << 7);
        u.tp.toff[tid][2] = (((ix0 << 7) + iy1) << 7);
        u.tp.toff[tid][3] = (((ix1 << 7) + iy1) << 7);
        const float wx1 = px1 - px, wx0 = px - px0;
        const float wy1 = py1 - py, wy0 = py - py0;
        u.tp.twgt[tid][0] = (f16)(wx1 * wy1); u.tp.twgt[tid][1] = (f16)(wx0 * wy1);
        u.tp.twgt[tid][2] = (f16)(wx1 * wy0); u.tp.twgt[tid][3] = (f16)(wx0 * wy0);
    }
    __syncthreads();   // B1

    // ---- sampling + maxpool, packed f16: lane -> 4 channels, half-wave -> line ----
    {
        const int h = lane >> 5, j = lane & 31;     // line parity, channel group
        const int li = wv * 2 + h;
        const f16* xbh = x + (((size_t)img) << 21) + 4 * j;
        #pragma unroll
        for (int t = 0; t < 8; ++t) {
            f16x4 m = {(f16)(-60000.f), (f16)(-60000.f), (f16)(-60000.f), (f16)(-60000.f)};
            #pragma unroll
            for (int s = 0; s < 4; ++s) {
                const int combo = li * 32 + t * 4 + s;
                const int4  off = *(const int4*)&u.tp.toff[combo][0];
                const f16x4 tw  = *(const f16x4*)&u.tp.twgt[combo][0];
                const f16x4 g00 = *(const f16x4*)(xbh + off.x);
                const f16x4 g10 = *(const f16x4*)(xbh + off.y);
                const f16x4 g01 = *(const f16x4*)(xbh + off.z);
                const f16x4 g11 = *(const f16x4*)(xbh + off.w);
                const f16x4 w0 = {tw[0], tw[0], tw[0], tw[0]};
                const f16x4 w1v = {tw[1], tw[1], tw[1], tw[1]};
                const f16x4 w2v = {tw[2], tw[2], tw[2], tw[2]};
                const f16x4 w3v = {tw[3], tw[3], tw[3], tw[3]};
                f16x4 v = g00 * w0 + g10 * w1v + g01 * w2v + g11 * w3v;
                m = hmax4(m, v);
            }
            *(f16x4*)&xp[li * 8 + t][4 * j] = m;
        }
    }
    __syncthreads();   // B2 (tuples dead; xp ready)

    // ---- zero h1 guard rows ----
    {
        const int r = tid >> 4, seg = tid & 15;
        const int row = (r >> 1) * 10 + (r & 1) * 9;
        *(unsigned long long*)&u.cv.h1[row][seg * 4] = 0ull;
    }

    // ---- conv1 + fused bn1/relu (packed f16) ----
    {
        const int o_lane = wv * 16 + n16;
        f32x4 acc1[4];
        #pragma unroll
        for (int nt = 0; nt < 4; ++nt) acc1[nt] = (f32x4){0.f, 0.f, 0.f, 0.f};
        #pragma unroll
        for (int ks = 0; ks < 4; ++ks) {
            const int k = ks * 32 + quad * 8;
            const f16x8 a  = *(const f16x8*)&w1f16[o_lane * 128 + k];
            const f16x8 s8 = *(const f16x8*)&s1h[k];
            const f16x8 t8 = *(const f16x8*)&t1h[k];
            #pragma unroll
            for (int nt = 0; nt < 4; ++nt) {
                const f16x8 raw = *(const f16x8*)&xp[nt * 16 + n16][k];
                const f16x8 bf = relu8(raw * s8 + t8);
                acc1[nt] = __builtin_amdgcn_mfma_f32_16x16x32_f16(a, bf, acc1[nt], 0, 0, 0);
            }
        }
        #pragma unroll
        for (int nt = 0; nt < 4; ++nt) {
            const int n = nt * 16 + n16;
            const int nprow = (n >> 3) * 10 + (n & 7) + 1;
            #pragma unroll
            for (int r = 0; r < 4; ++r) {
                const int o = wv * 16 + quad * 4 + r;
                const float v = fmaxf((acc1[nt][r] + b1f[o]) * s2f[o] + t2f[o], 0.f);
                u.cv.h1[nprow][o] = (f16)v;
            }
        }
    }
    __syncthreads();   // B3

    // ---- conv2: 3 shifted [64x64] matmuls ----
    {
        const int o_lane = wv * 16 + n16;
        f32x4 acc2[4];
        #pragma unroll
        for (int nt = 0; nt < 4; ++nt) acc2[nt] = (f32x4){0.f, 0.f, 0.f, 0.f};
        #pragma unroll
        for (int d = 0; d < 3; ++d) {
            const f16* A2 = w2f16 + d * 4096;
            #pragma unroll
            for (int ks = 0; ks < 2; ++ks) {
                const int k = ks * 32 + quad * 8;
                const f16x8 a = *(const f16x8*)&A2[o_lane * 64 + k];
                #pragma unroll
                for (int nt = 0; nt < 4; ++nt) {
                    const int n = nt * 16 + n16;
                    const int row = (n >> 3) * 10 + (n & 7) + d;
                    const f16x8 bf = *(const f16x8*)&u.cv.h1[row][k];
                    acc2[nt] = __builtin_amdgcn_mfma_f32_16x16x32_f16(a, bf, acc2[nt], 0, 0, 0);
                }
            }
        }
        #pragma unroll
        for (int nt = 0; nt < 4; ++nt) {
            const int n = nt * 16 + n16;
            #pragma unroll
            for (int r = 0; r < 4; ++r) {
                const int o = wv * 16 + quad * 4 + r;
                const float v = fmaxf((acc2[nt][r] + b2f[o]) * s3f[o] + t3f[o], 0.f);
                u.cv.h2[n][o] = (f16)v;
            }
        }
    }
    __syncthreads();   // B4

    // ---- conv3 + residual + relu + fc2 ----
    {
        // per-lane fc2 weights: (n&7) == n16&7 is lane-constant -> 8 scalars
        const int col = n16 & 7, obase = wv * 16 + quad * 4;
        float fcv[2][4];
        #pragma unroll
        for (int h = 0; h < 2; ++h)
            #pragma unroll
            for (int r = 0; r < 4; ++r)
                fcv[h][r] = fc2w[(h * 64 + obase + r) * 8 + col];

        f32x4 acc3[2][4];
        #pragma unroll
        for (int h = 0; h < 2; ++h)
            #pragma unroll
            for (int nt = 0; nt < 4; ++nt) acc3[h][nt] = (f32x4){0.f, 0.f, 0.f, 0.f};
        #pragma unroll
        for (int ks = 0; ks < 2; ++ks) {
            const int k = ks * 32 + quad * 8;
            const f16x8 a0 = *(const f16x8*)&w3f16[(wv * 16 + n16) * 64 + k];
            const f16x8 a1 = *(const f16x8*)&w3f16[(64 + wv * 16 + n16) * 64 + k];
            #pragma unroll
            for (int nt = 0; nt < 4; ++nt) {
                const f16x8 bf = *(const f16x8*)&u.cv.h2[nt * 16 + n16][k];
                acc3[0][nt] = __builtin_amdgcn_mfma_f32_16x16x32_f16(a0, bf, acc3[0][nt], 0, 0, 0);
                acc3[1][nt] = __builtin_amdgcn_mfma_f32_16x16x32_f16(a1, bf, acc3[1][nt], 0, 0, 0);
            }
        }
        float part[4] = {0.f, 0.f, 0.f, 0.f};
        #pragma unroll
        for (int h = 0; h < 2; ++h) {
            const float4 bq = *(const float4*)&b3f[h * 64 + obase];
            const float bqa[4] = {bq.x, bq.y, bq.z, bq.w};
            #pragma unroll
            for (int nt = 0; nt < 4; ++nt) {
                const int n = nt * 16 + n16;
                const f16x4 rx = *(const f16x4*)&xp[n][h * 64 + obase];
                float p = 0.f;
                #pragma unroll
                for (int r = 0; r < 4; ++r) {
                    float v = acc3[h][nt][r] + bqa[r] + (float)rx[r];
                    v = fmaxf(v, 0.f);
                    p += v * fcv[h][r];
                }
                part[nt] += p;
            }
        }
        #pragma unroll
        for (int off_i = 0; off_i < 5; ++off_i) {
            const int off = (int[]){1, 2, 4, 16, 32}[off_i];
            part[0] += __shfl_xor(part[0], off, 64);
            part[1] += __shfl_xor(part[1], off, 64);
            part[2] += __shfl_xor(part[2], off, 64);
            part[3] += __shfl_xor(part[3], off, 64);
        }
        if ((lane & 55) == 0) {          // lanes 0 and 8
            const int par = (lane >> 3) & 1;
            wsum[wv][0 + par] = part[0];
            wsum[wv][2 + par] = part[1];
            wsum[wv][4 + par] = part[2];
            wsum[wv][6 + par] = part[3];
        }
    }
    __syncthreads();   // B5

    if (tid < 8) {
        const float s = wsum[0][tid] + wsum[1][tid] + wsum[2][tid] + wsum[3][tid];
        out[img * 2048 + mblk * 8 + tid] = s + fc2b[0];
    }
}

// ---------------------------------------------------------------------------
extern "C" void kernel_launch(void* const* d_in, const int* in_sizes, int n_in,
                              void* d_out, int out_size, void* d_ws, size_t ws_size,
                              hipStream_t stream) {
    const float* feature = (const float*)d_in[0];
    const float* lines   = (const float*)d_in[1];
    const float* fc1_w   = (const float*)d_in[2];
    const float* fc1_b   = (const float*)d_in[3];
    const float* bn1g    = (const float*)d_in[4];
    const float* bn1b    = (const float*)d_in[5];
    const float* bn1m    = (const float*)d_in[6];
    const float* bn1v    = (const float*)d_in[7];
    const float* w1      = (const float*)d_in[8];
    const float* b1      = (const float*)d_in[9];
    const float* bn2g    = (const float*)d_in[10];
    const float* bn2b    = (const float*)d_in[11];
    const float* bn2m    = (const float*)d_in[12];
    const float* bn2v    = (const float*)d_in[13];
    const float* w2      = (const float*)d_in[14];
    const float* b2      = (const float*)d_in[15];
    const float* bn3g    = (const float*)d_in[16];
    const float* bn3b    = (const float*)d_in[17];
    const float* bn3m    = (const float*)d_in[18];
    const float* bn3v    = (const float*)d_in[19];
    const float* w3      = (const float*)d_in[20];
    const float* b3      = (const float*)d_in[21];
    const float* fc2w    = (const float*)d_in[22];
    const float* fc2b    = (const float*)d_in[23];

    f16* xmap = (f16*)d_ws;                                      // 32 MiB
    f16* wsp  = (f16*)((char*)d_ws + (size_t)32 * 1024 * 1024);  // 120 KiB

    wprep_kernel<<<240, 256, 0, stream>>>(fc1_w, w1, w2, w3, wsp);
    fc1_mfma<<<512, 512, 0, stream>>>(feature, wsp, fc1_b, xmap);
    loi_kernel<<<2048, 256, 0, stream>>>(xmap, lines, wsp,
                                         bn1g, bn1b, bn1m, bn1v, b1,
                                         bn2g, bn2b, bn2m, bn2v, b2,
                                         bn3g, bn3b, bn3m, bn3v, b3,
                                         fc2w, fc2b, (float*)d_out);
}